// Round 3
// baseline (406.229 us; speedup 1.0000x reference)
//
#include <hip/hip_runtime.h>
#include <cstdint>
#include <cstddef>

// Problem constants
#define B_  16
#define T_  2048
#define DIN 1024
#define DPJ 512
#define DOUT 1024
#define LORD 20
#define HALO (LORD - 1)             // 19
#define M_ROWS (B_ * T_)            // 32768
#define OUT0_ELEMS ((size_t)M_ROWS * DOUT)          // 33554432
#define CACHE_ELEMS ((size_t)B_ * DPJ * (LORD - 1)) // 155648

typedef __bf16 bf16_t;
typedef __bf16 bf16x2 __attribute__((ext_vector_type(2)));
typedef __bf16 bf16x4 __attribute__((ext_vector_type(4)));
typedef __bf16 bf16x8 __attribute__((ext_vector_type(8)));
typedef float  f32x4  __attribute__((ext_vector_type(4)));

// ---------------------------------------------------------------------------
// async global->LDS, 16B per lane. lds pointer must be wave-uniform; HW puts
// lane i's 16B at lds_base + i*16.
__device__ __forceinline__ void async_load16(const bf16_t* g, bf16_t* lds_base) {
    __builtin_amdgcn_global_load_lds(
        (const __attribute__((address_space(1))) unsigned int*)g,
        (__attribute__((address_space(3))) unsigned int*)lds_base,
        16, 0, 0);
}

// ---------------------------------------------------------------------------
// Both weight transposes in one launch.
// W_lin (DIN x DPJ) -> WlT (DPJ x DIN) bf16 ; W_aff (DPJ x DOUT) -> WaT (DOUT x DPJ)
__global__ __launch_bounds__(256) void prep_weights(
    const float* __restrict__ Wl, const float* __restrict__ Wa,
    bf16_t* __restrict__ WlT, bf16_t* __restrict__ WaT) {
    int idx = blockIdx.x * 256 + threadIdx.x;
    const int n1 = DIN * DPJ;
    if (idx < n1) {
        int k = idx / DPJ, n = idx - k * DPJ;
        WlT[(size_t)n * DIN + k] = (bf16_t)Wl[idx];
    } else {
        int j = idx - n1;
        if (j < DPJ * DOUT) {
            int k = j / DOUT, n = j - k * DOUT;
            WaT[(size_t)n * DPJ + k] = (bf16_t)Wa[j];
        }
    }
}

// ---------------------------------------------------------------------------
// GEMM1 with fused f32->bf16 cast on A: C_bf16[M,N] = f32 A[M,K] * Bt[N,K]^T.
// 128x128 tile, BK=64, 256 thr (4 waves), wave = 64x64 as 4x4 of 16x16x32 MFMA.
// A staged synchronously: 8 coalesced float4 loads (16 lanes = 256B row seg),
// packed cvt, ds_write into the XOR-swizzled chunk layout. B staged async.
// LDS swizzle: logical (row r, 8-elem chunk j) at physical chunk r*8+(j^(r&7)).
__global__ __launch_bounds__(256) void gemm_f32a(
    const float* __restrict__ A, const bf16_t* __restrict__ Bt,
    bf16_t* __restrict__ C, const int M, const int N, const int K) {
    __shared__ bf16_t sA[128 * 64];
    __shared__ bf16_t sB[128 * 64];

    const int tid  = threadIdx.x;
    const int lane = tid & 63;
    const int wave = tid >> 6;
    const int row0 = blockIdx.x * 128;
    const int col0 = blockIdx.y * 128;

    // B staging (async)
    const int lr   = lane >> 3;
    const int jsw  = (lane & 7) ^ lr;
    const bf16_t* gB0 = Bt + (size_t)(col0 + wave * 32 + lr) * K + jsw * 8;
    bf16_t* lB0 = sB + wave * 2048;

    // A staging (f32, coalesced): load i covers rows i*16 + (tid>>4), col4 tid&15
    const int ar  = tid >> 4;            // 0..15
    const int ac4 = tid & 15;            // float4 index within 64-wide K slab
    const float* gA0 = A + (size_t)(row0 + ar) * K + ac4 * 4;
    const int aj = ac4 >> 1, ah = ac4 & 1;
    const int asw = ((aj ^ (ar & 7)) << 3) + ah * 4;   // (i*16+ar)&7 == ar&7

    // compute-side fragment coords
    const int wm = (wave >> 1) * 64;
    const int wn = (wave & 1) * 64;
    const int fr = lane & 15;
    const int fk = lane >> 4;

    const f32x4 zero = {0.f, 0.f, 0.f, 0.f};
    f32x4 acc[4][4];
#pragma unroll
    for (int mt = 0; mt < 4; ++mt)
#pragma unroll
        for (int nt = 0; nt < 4; ++nt) acc[mt][nt] = zero;

    for (int k0 = 0; k0 < K; k0 += 64) {
        __syncthreads();                  // prior compute done before overwrite
        float4 av[8];
#pragma unroll
        for (int i = 0; i < 8; ++i)
            av[i] = *(const float4*)(gA0 + (size_t)i * 16 * K + k0);
#pragma unroll
        for (int c = 0; c < 4; ++c)
            async_load16(gB0 + (size_t)c * 8 * K + k0, lB0 + c * 512);
#pragma unroll
        for (int i = 0; i < 8; ++i) {
            bf16x4 o = { (bf16_t)av[i].x, (bf16_t)av[i].y,
                         (bf16_t)av[i].z, (bf16_t)av[i].w };
            *(bf16x4*)(sA + (i * 16 + ar) * 64 + asw) = o;
        }
        __syncthreads();                  // drains lgkm (ds_write) + vmcnt (async)

#pragma unroll
        for (int h = 0; h < 2; ++h) {
            bf16x8 af[4], bfr[4];
#pragma unroll
            for (int mt = 0; mt < 4; ++mt) {
                int r = wm + mt * 16 + fr;
                int j = h * 4 + fk;
                af[mt] = *(const bf16x8*)(sA + r * 64 + ((j ^ (r & 7)) << 3));
            }
#pragma unroll
            for (int nt = 0; nt < 4; ++nt) {
                int r = wn + nt * 16 + fr;
                int j = h * 4 + fk;
                bfr[nt] = *(const bf16x8*)(sB + r * 64 + ((j ^ (r & 7)) << 3));
            }
#pragma unroll
            for (int mt = 0; mt < 4; ++mt)
#pragma unroll
                for (int nt = 0; nt < 4; ++nt)
                    acc[mt][nt] = __builtin_amdgcn_mfma_f32_16x16x32_bf16(
                        af[mt], bfr[nt], acc[mt][nt], 0, 0, 0);
        }
    }

    // epilogue: C/D layout col=lane&15, row=(lane>>4)*4+reg  [m89]
    const int er = row0 + wm + (lane >> 4) * 4;
    const int ec = col0 + wn + (lane & 15);
#pragma unroll
    for (int mt = 0; mt < 4; ++mt)
#pragma unroll
        for (int nt = 0; nt < 4; ++nt)
#pragma unroll
            for (int rr = 0; rr < 4; ++rr)
                C[(size_t)(er + mt * 16 + rr) * N + (ec + nt * 16)] =
                    (bf16_t)acc[mt][nt][rr];
}

// ---------------------------------------------------------------------------
// GEMM2: bf16 A (async staging), f32 out with bias+ReLU.
__global__ __launch_bounds__(256) void gemm_bt_relu(
    const bf16_t* __restrict__ A, const bf16_t* __restrict__ Bt,
    float* __restrict__ C, const float* __restrict__ bias,
    const int M, const int N, const int K) {
    __shared__ bf16_t sA[128 * 64];
    __shared__ bf16_t sB[128 * 64];

    const int tid  = threadIdx.x;
    const int lane = tid & 63;
    const int wave = tid >> 6;
    const int row0 = blockIdx.x * 128;
    const int col0 = blockIdx.y * 128;

    const int lr   = lane >> 3;
    const int jsw  = (lane & 7) ^ lr;
    const bf16_t* gA0 = A  + (size_t)(row0 + wave * 32 + lr) * K + jsw * 8;
    const bf16_t* gB0 = Bt + (size_t)(col0 + wave * 32 + lr) * K + jsw * 8;
    bf16_t* lA0 = sA + wave * 2048;
    bf16_t* lB0 = sB + wave * 2048;

    const int wm = (wave >> 1) * 64;
    const int wn = (wave & 1) * 64;
    const int fr = lane & 15;
    const int fk = lane >> 4;

    const f32x4 zero = {0.f, 0.f, 0.f, 0.f};
    f32x4 acc[4][4];
#pragma unroll
    for (int mt = 0; mt < 4; ++mt)
#pragma unroll
        for (int nt = 0; nt < 4; ++nt) acc[mt][nt] = zero;

    for (int k0 = 0; k0 < K; k0 += 64) {
        __syncthreads();
#pragma unroll
        for (int c = 0; c < 4; ++c) {
            async_load16(gA0 + (size_t)c * 8 * K + k0, lA0 + c * 512);
            async_load16(gB0 + (size_t)c * 8 * K + k0, lB0 + c * 512);
        }
        __syncthreads();

#pragma unroll
        for (int h = 0; h < 2; ++h) {
            bf16x8 af[4], bfr[4];
#pragma unroll
            for (int mt = 0; mt < 4; ++mt) {
                int r = wm + mt * 16 + fr;
                int j = h * 4 + fk;
                af[mt] = *(const bf16x8*)(sA + r * 64 + ((j ^ (r & 7)) << 3));
            }
#pragma unroll
            for (int nt = 0; nt < 4; ++nt) {
                int r = wn + nt * 16 + fr;
                int j = h * 4 + fk;
                bfr[nt] = *(const bf16x8*)(sB + r * 64 + ((j ^ (r & 7)) << 3));
            }
#pragma unroll
            for (int mt = 0; mt < 4; ++mt)
#pragma unroll
                for (int nt = 0; nt < 4; ++nt)
                    acc[mt][nt] = __builtin_amdgcn_mfma_f32_16x16x32_bf16(
                        af[mt], bfr[nt], acc[mt][nt], 0, 0, 0);
        }
    }

    const int er = row0 + wm + (lane >> 4) * 4;
    const int ec = col0 + wn + (lane & 15);
#pragma unroll
    for (int nt = 0; nt < 4; ++nt) {
        float bb = bias[ec + nt * 16];
#pragma unroll
        for (int mt = 0; mt < 4; ++mt)
#pragma unroll
            for (int rr = 0; rr < 4; ++rr) {
                float v = acc[mt][nt][rr] + bb;
                C[(size_t)(er + mt * 16 + rr) * N + (ec + nt * 16)] =
                    v > 0.f ? v : 0.f;
            }
    }
}

// ---------------------------------------------------------------------------
// Depthwise causal conv + residual, LDS-tiled with rolling register window.
#define TT 64
#define PPT 128
__global__ __launch_bounds__(256) void dwconv_tiled(
    const bf16_t* __restrict__ x, const float* __restrict__ cache,
    const float* __restrict__ cw, bf16_t* __restrict__ m) {
    __shared__ float sx[(TT + HALO) * PPT];   // 83*128*4 = 42.5 KB

    const int tid = threadIdx.x;
    const int t0  = blockIdx.x * TT;
    const int b   = blockIdx.y;
    const int p0  = blockIdx.z * PPT;

    // ---- stage rows t0-19 .. t0+63, cols p0..p0+127 (8 bf16 per chunk) ----
    for (int c = tid; c < (TT + HALO) * PPT / 8; c += 256) {   // 1328 chunks
        int r    = c >> 4;            // 0..82
        int col  = (c & 15) << 3;     // 0,8,...,120
        int trow = t0 - HALO + r;
        float* dst = sx + r * PPT + col;
        if (trow >= 0) {
            bf16x8 v = *(const bf16x8*)(x + ((size_t)(b * T_ + trow)) * DPJ + p0 + col);
#pragma unroll
            for (int i = 0; i < 8; ++i) dst[i] = (float)v[i];
        } else {
#pragma unroll
            for (int i = 0; i < 8; ++i)
                dst[i] = cache[((size_t)b * DPJ + p0 + col + i) * HALO + (trow + HALO)];
        }
    }
    __syncthreads();

    // ---- compute: thread -> channel pair, 16 timesteps, rolling window ----
    const int pp   = tid & 63;
    const int half = tid >> 6;
    const int tb   = half * 16;
    const float2* sx2 = (const float2*)sx;   // [83][64]

    const int pg = p0 + 2 * pp;
    float2 w[LORD];
#pragma unroll
    for (int l = 0; l < LORD; ++l) {
        w[l].x = cw[pg * LORD + l];
        w[l].y = cw[(pg + 1) * LORD + l];
    }

    float2 win[LORD];
#pragma unroll
    for (int i = 0; i < HALO; ++i) win[i] = sx2[(tb + i) * 64 + pp];

#pragma unroll
    for (int tl = 0; tl < 16; ++tl) {
        float2 nv = sx2[(tb + tl + HALO) * 64 + pp];
        win[(tl + HALO) % LORD] = nv;
        float2 s = nv;                         // residual x[b,t,p]
#pragma unroll
        for (int l = 0; l < LORD; ++l) {
            float2 v = win[(tl + l) % LORD];
            s.x += w[l].x * v.x;
            s.y += w[l].y * v.y;
        }
        bf16x2 o = { (bf16_t)s.x, (bf16_t)s.y };
        *(bf16x2*)(m + ((size_t)(b * T_ + t0 + tb + tl)) * DPJ + pg) = o;
    }
}

// out_cache[b,p,j] = x[b, T-19+j, p]
__global__ __launch_bounds__(256) void cache_out(
    const bf16_t* __restrict__ x, float* __restrict__ oc) {
    int idx = blockIdx.x * 256 + threadIdx.x;
    if (idx < (int)CACHE_ELEMS) {
        int b = idx / (DPJ * (LORD - 1));
        int rem = idx % (DPJ * (LORD - 1));
        int p = rem / (LORD - 1);
        int j = rem % (LORD - 1);
        oc[idx] = (float)x[((size_t)(b * T_ + T_ - (LORD - 1) + j)) * DPJ + p];
    }
}

// ---------------------------------------------------------------------------
extern "C" void kernel_launch(void* const* d_in, const int* in_sizes, int n_in,
                              void* d_out, int out_size, void* d_ws, size_t ws_size,
                              hipStream_t stream) {
    const float* input    = (const float*)d_in[0];  // (16,2048,1024)
    const float* in_cache = (const float*)d_in[1];  // (16,512,19)
    const float* W_lin    = (const float*)d_in[2];  // (1024,512)
    const float* conv_w   = (const float*)d_in[3];  // (512,20)
    const float* W_aff    = (const float*)d_in[4];  // (512,1024)
    const float* b_aff    = (const float*)d_in[5];  // (1024,)
    float* out = (float*)d_out;                     // 33554432 + 155648 f32

    // workspace layout (bytes):
    //   [0, 32MB)       x bf16 (32768x512)
    //   [32MB, 64MB)    m bf16 (32768x512)
    //   [64MB, +1MB)    W_lin^T bf16 (512x1024)
    //   [65MB, +0.5MB)  W_aff^T bf16 (1024x512)
    char* ws = (char*)d_ws;
    bf16_t* x_buf = (bf16_t*)(ws);
    bf16_t* m_buf = (bf16_t*)(ws + 33554432);
    bf16_t* WlinT = (bf16_t*)(ws + 67108864);
    bf16_t* WaffT = (bf16_t*)(ws + 67108864 + 1048576);

    // 1. weight prep (both transposes, one launch)
    prep_weights<<<(DIN * DPJ + DPJ * DOUT + 255) / 256, 256, 0, stream>>>(
        W_lin, W_aff, WlinT, WaffT);

    // 2. x = bf16(input) @ W_lin   (M=32768, N=512, K=1024), fused cast
    gemm_f32a<<<dim3(M_ROWS / 128, DPJ / 128), 256, 0, stream>>>(
        input, WlinT, x_buf, M_ROWS, DPJ, DIN);

    // 3. depthwise conv + residual -> m ; out_cache
    dwconv_tiled<<<dim3(T_ / TT, B_, DPJ / PPT), 256, 0, stream>>>(
        x_buf, in_cache, conv_w, m_buf);
    cache_out<<<(int)((CACHE_ELEMS + 255) / 256), 256, 0, stream>>>(
        x_buf, out + OUT0_ELEMS);

    // 4. out = relu(m @ W_aff + b)  (M=32768, N=1024, K=512), f32 out
    gemm_bt_relu<<<dim3(M_ROWS / 128, DOUT / 128), 256, 0, stream>>>(
        m_buf, WaffT, out, b_aff, M_ROWS, DOUT, DPJ);
}

// Round 4
// 371.778 us; speedup vs baseline: 1.0927x; 1.0927x over previous
//
#include <hip/hip_runtime.h>
#include <cstdint>
#include <cstddef>

// Problem constants
#define B_  16
#define T_  2048
#define DIN 1024
#define DPJ 512
#define DOUT 1024
#define LORD 20
#define HALO (LORD - 1)             // 19
#define M_ROWS (B_ * T_)            // 32768
#define OUT0_ELEMS ((size_t)M_ROWS * DOUT)          // 33554432
#define CACHE_ELEMS ((size_t)B_ * DPJ * (LORD - 1)) // 155648

typedef __bf16 bf16_t;
typedef __bf16 bf16x2 __attribute__((ext_vector_type(2)));
typedef __bf16 bf16x4 __attribute__((ext_vector_type(4)));
typedef __bf16 bf16x8 __attribute__((ext_vector_type(8)));
typedef float  f32x4  __attribute__((ext_vector_type(4)));

// ---------------------------------------------------------------------------
// async global->LDS, 16B per lane. lds pointer must be wave-uniform; HW puts
// lane i's 16B at lds_base + i*16.
__device__ __forceinline__ void async_load16(const void* g, void* lds_base) {
    __builtin_amdgcn_global_load_lds(
        (const __attribute__((address_space(1))) unsigned int*)g,
        (__attribute__((address_space(3))) unsigned int*)lds_base,
        16, 0, 0);
}

// ---------------------------------------------------------------------------
// Both weight transposes in one launch.
// W_lin (DIN x DPJ) -> WlT (DPJ x DIN) bf16 ; W_aff (DPJ x DOUT) -> WaT (DOUT x DPJ)
__global__ __launch_bounds__(256) void prep_weights(
    const float* __restrict__ Wl, const float* __restrict__ Wa,
    bf16_t* __restrict__ WlT, bf16_t* __restrict__ WaT) {
    int idx = blockIdx.x * 256 + threadIdx.x;
    const int n1 = DIN * DPJ;
    if (idx < n1) {
        int k = idx / DPJ, n = idx - k * DPJ;
        WlT[(size_t)n * DIN + k] = (bf16_t)Wl[idx];
    } else {
        int j = idx - n1;
        if (j < DPJ * DOUT) {
            int k = j / DOUT, n = j - k * DOUT;
            WaT[(size_t)n * DPJ + k] = (bf16_t)Wa[j];
        }
    }
}

// ---------------------------------------------------------------------------
// GEMM1, fused f32->bf16 cast on A, ASYNC staging for both operands.
// C_bf16[M,N] = bf16(A_f32[M,K]) * Bt[N,K]^T.
// A staged as f32 into LDS via global_load_lds (linear lane placement);
// the global k-chunk index is XOR-swizzled so the linear LDS layout equals
// the swizzled layout the fragment reads expect:
//   physical 16B chunk p at row r holds logical chunk p ^ (r&15).
// Fragment read converts f32x8 -> bf16x8 in registers (RNE, same as a cast
// kernel would produce).
// B: bf16, 8-chunk rows, physical chunk p holds logical p ^ (r&7) (as before).
// Grid: blockIdx.x = N-tile (fastest) so sibling blocks share the A slice.
__global__ __launch_bounds__(256) void gemm1_fused(
    const float* __restrict__ A, const bf16_t* __restrict__ Bt,
    bf16_t* __restrict__ C, const int M, const int N, const int K) {
    __shared__ float  sAf[128 * 64];   // 32 KB
    __shared__ bf16_t sB [128 * 64];   // 16 KB

    const int tid  = threadIdx.x;
    const int lane = tid & 63;
    const int wave = tid >> 6;
    const int col0 = blockIdx.x * 128;   // N tile (fastest-varying)
    const int row0 = blockIdx.y * 128;   // M tile

    // ---- A staging: 8 calls/wave, call c covers rows wave*32 + c*4 + (lane>>4)
    const int hi = lane >> 4;            // 0..3
    const int lo = lane & 15;            // 0..15
    size_t aoff[8];
#pragma unroll
    for (int c = 0; c < 8; ++c) {
        int rloc  = wave * 32 + c * 4 + hi;
        int chunk = lo ^ (((c & 3) << 2) | hi);   // (c*4+hi)&15 == ((c&3)<<2)|hi
        aoff[c] = (size_t)(row0 + rloc) * K + chunk * 4;
    }
    float* lA[8];
#pragma unroll
    for (int c = 0; c < 8; ++c) lA[c] = sAf + (wave * 32 + c * 4) * 64;

    // ---- B staging: 4 calls/wave (bf16, 8-elem chunks, ^(r&7) swizzle)
    const int lr  = lane >> 3;
    const int jsw = (lane & 7) ^ lr;
    const bf16_t* gB0 = Bt + (size_t)(col0 + wave * 32 + lr) * K + jsw * 8;
    bf16_t* lB0 = sB + wave * 2048;

    // compute-side fragment coords
    const int wm = (wave >> 1) * 64;
    const int wn = (wave & 1) * 64;
    const int fr = lane & 15;
    const int fk = lane >> 4;

    const f32x4 zero = {0.f, 0.f, 0.f, 0.f};
    f32x4 acc[4][4];
#pragma unroll
    for (int mt = 0; mt < 4; ++mt)
#pragma unroll
        for (int nt = 0; nt < 4; ++nt) acc[mt][nt] = zero;

    for (int k0 = 0; k0 < K; k0 += 64) {
        __syncthreads();
#pragma unroll
        for (int c = 0; c < 8; ++c) async_load16(A + aoff[c] + k0, lA[c]);
#pragma unroll
        for (int c = 0; c < 4; ++c)
            async_load16(gB0 + (size_t)c * 8 * K + k0, lB0 + c * 512);
        __syncthreads();   // drains vmcnt

#pragma unroll
        for (int h = 0; h < 2; ++h) {
            bf16x8 af[4], bfr[4];
#pragma unroll
            for (int mt = 0; mt < 4; ++mt) {
                int r  = wm + mt * 16 + fr;
                int c0 = h * 8 + fk * 2;           // logical f32 chunk
                // r&15 == fr
                f32x4 a0 = *(const f32x4*)(sAf + r * 64 + ((c0 ^ fr) << 2));
                f32x4 a1 = *(const f32x4*)(sAf + r * 64 + (((c0 + 1) ^ fr) << 2));
                bf16x8 v = { (bf16_t)a0[0], (bf16_t)a0[1], (bf16_t)a0[2], (bf16_t)a0[3],
                             (bf16_t)a1[0], (bf16_t)a1[1], (bf16_t)a1[2], (bf16_t)a1[3] };
                af[mt] = v;
            }
#pragma unroll
            for (int nt = 0; nt < 4; ++nt) {
                int r = wn + nt * 16 + fr;
                int j = h * 4 + fk;
                bfr[nt] = *(const bf16x8*)(sB + r * 64 + ((j ^ (r & 7)) << 3));
            }
#pragma unroll
            for (int mt = 0; mt < 4; ++mt)
#pragma unroll
                for (int nt = 0; nt < 4; ++nt)
                    acc[mt][nt] = __builtin_amdgcn_mfma_f32_16x16x32_bf16(
                        af[mt], bfr[nt], acc[mt][nt], 0, 0, 0);
        }
    }

    // epilogue: C/D layout col=lane&15, row=(lane>>4)*4+reg  [m89]
    const int er = row0 + wm + (lane >> 4) * 4;
    const int ec = col0 + wn + (lane & 15);
#pragma unroll
    for (int mt = 0; mt < 4; ++mt)
#pragma unroll
        for (int nt = 0; nt < 4; ++nt)
#pragma unroll
            for (int rr = 0; rr < 4; ++rr)
                C[(size_t)(er + mt * 16 + rr) * N + (ec + nt * 16)] =
                    (bf16_t)acc[mt][nt][rr];
}

// ---------------------------------------------------------------------------
// GEMM2: bf16 A (async staging), f32 out with bias+ReLU.  N-tile fastest.
__global__ __launch_bounds__(256) void gemm_bt_relu(
    const bf16_t* __restrict__ A, const bf16_t* __restrict__ Bt,
    float* __restrict__ C, const float* __restrict__ bias,
    const int M, const int N, const int K) {
    __shared__ bf16_t sA[128 * 64];
    __shared__ bf16_t sB[128 * 64];

    const int tid  = threadIdx.x;
    const int lane = tid & 63;
    const int wave = tid >> 6;
    const int col0 = blockIdx.x * 128;   // N tile (fastest-varying)
    const int row0 = blockIdx.y * 128;   // M tile

    const int lr   = lane >> 3;
    const int jsw  = (lane & 7) ^ lr;
    const bf16_t* gA0 = A  + (size_t)(row0 + wave * 32 + lr) * K + jsw * 8;
    const bf16_t* gB0 = Bt + (size_t)(col0 + wave * 32 + lr) * K + jsw * 8;
    bf16_t* lA0 = sA + wave * 2048;
    bf16_t* lB0 = sB + wave * 2048;

    const int wm = (wave >> 1) * 64;
    const int wn = (wave & 1) * 64;
    const int fr = lane & 15;
    const int fk = lane >> 4;

    const f32x4 zero = {0.f, 0.f, 0.f, 0.f};
    f32x4 acc[4][4];
#pragma unroll
    for (int mt = 0; mt < 4; ++mt)
#pragma unroll
        for (int nt = 0; nt < 4; ++nt) acc[mt][nt] = zero;

    for (int k0 = 0; k0 < K; k0 += 64) {
        __syncthreads();
#pragma unroll
        for (int c = 0; c < 4; ++c) {
            async_load16(gA0 + (size_t)c * 8 * K + k0, lA0 + c * 512);
            async_load16(gB0 + (size_t)c * 8 * K + k0, lB0 + c * 512);
        }
        __syncthreads();

#pragma unroll
        for (int h = 0; h < 2; ++h) {
            bf16x8 af[4], bfr[4];
#pragma unroll
            for (int mt = 0; mt < 4; ++mt) {
                int r = wm + mt * 16 + fr;
                int j = h * 4 + fk;
                af[mt] = *(const bf16x8*)(sA + r * 64 + ((j ^ (r & 7)) << 3));
            }
#pragma unroll
            for (int nt = 0; nt < 4; ++nt) {
                int r = wn + nt * 16 + fr;
                int j = h * 4 + fk;
                bfr[nt] = *(const bf16x8*)(sB + r * 64 + ((j ^ (r & 7)) << 3));
            }
#pragma unroll
            for (int mt = 0; mt < 4; ++mt)
#pragma unroll
                for (int nt = 0; nt < 4; ++nt)
                    acc[mt][nt] = __builtin_amdgcn_mfma_f32_16x16x32_bf16(
                        af[mt], bfr[nt], acc[mt][nt], 0, 0, 0);
        }
    }

    const int er = row0 + wm + (lane >> 4) * 4;
    const int ec = col0 + wn + (lane & 15);
#pragma unroll
    for (int nt = 0; nt < 4; ++nt) {
        float bb = bias[ec + nt * 16];
#pragma unroll
        for (int mt = 0; mt < 4; ++mt)
#pragma unroll
            for (int rr = 0; rr < 4; ++rr) {
                float v = acc[mt][nt][rr] + bb;
                C[(size_t)(er + mt * 16 + rr) * N + (ec + nt * 16)] =
                    v > 0.f ? v : 0.f;
            }
    }
}

// ---------------------------------------------------------------------------
// Depthwise causal conv + residual, LDS-tiled, rolling register window.
// Last-t blocks also emit out_cache from their staged LDS (f32).
#define TT 64
#define PPT 128
__global__ __launch_bounds__(256) void dwconv_tiled(
    const bf16_t* __restrict__ x, const float* __restrict__ cache,
    const float* __restrict__ cw, bf16_t* __restrict__ m,
    float* __restrict__ oc) {
    __shared__ float sx[(TT + HALO) * PPT];   // 83*128*4 = 42.5 KB

    const int tid = threadIdx.x;
    const int t0  = blockIdx.x * TT;
    const int b   = blockIdx.y;
    const int p0  = blockIdx.z * PPT;

    // ---- stage rows t0-19 .. t0+63, cols p0..p0+127 (8 bf16 per chunk) ----
    for (int c = tid; c < (TT + HALO) * PPT / 8; c += 256) {   // 1328 chunks
        int r    = c >> 4;            // 0..82
        int col  = (c & 15) << 3;     // 0,8,...,120
        int trow = t0 - HALO + r;
        float* dst = sx + r * PPT + col;
        if (trow >= 0) {
            bf16x8 v = *(const bf16x8*)(x + ((size_t)(b * T_ + trow)) * DPJ + p0 + col);
#pragma unroll
            for (int i = 0; i < 8; ++i) dst[i] = (float)v[i];
        } else {
#pragma unroll
            for (int i = 0; i < 8; ++i)
                dst[i] = cache[((size_t)b * DPJ + p0 + col + i) * HALO + (trow + HALO)];
        }
    }
    __syncthreads();

    // ---- compute: thread -> channel pair, 16 timesteps, rolling window ----
    const int pp   = tid & 63;
    const int half = tid >> 6;
    const int tb   = half * 16;
    const float2* sx2 = (const float2*)sx;   // [83][64]

    const int pg = p0 + 2 * pp;
    float2 w[LORD];
#pragma unroll
    for (int l = 0; l < LORD; ++l) {
        w[l].x = cw[pg * LORD + l];
        w[l].y = cw[(pg + 1) * LORD + l];
    }

    float2 win[LORD];
#pragma unroll
    for (int i = 0; i < HALO; ++i) win[i] = sx2[(tb + i) * 64 + pp];

#pragma unroll
    for (int tl = 0; tl < 16; ++tl) {
        float2 nv = sx2[(tb + tl + HALO) * 64 + pp];
        win[(tl + HALO) % LORD] = nv;
        float2 s = nv;                         // residual x[b,t,p]
#pragma unroll
        for (int l = 0; l < LORD; ++l) {
            float2 v = win[(tl + l) % LORD];
            s.x += w[l].x * v.x;
            s.y += w[l].y * v.y;
        }
        bf16x2 o = { (bf16_t)s.x, (bf16_t)s.y };
        *(bf16x2*)(m + ((size_t)(b * T_ + t0 + tb + tl)) * DPJ + pg) = o;
    }

    // ---- fused out_cache: out_cache[b,p,j] = x[b, T-19+j, p], from LDS ----
    // Last t-tile has rows T-19..T-1 staged at r = 64..82.
    if (blockIdx.x == (T_ / TT) - 1) {
        for (int i = tid; i < PPT * HALO; i += 256) {
            int pl = i / HALO;
            int j  = i - pl * HALO;
            oc[((size_t)b * DPJ + p0 + pl) * HALO + j] = sx[(64 + j) * PPT + pl];
        }
    }
}

// ---------------------------------------------------------------------------
extern "C" void kernel_launch(void* const* d_in, const int* in_sizes, int n_in,
                              void* d_out, int out_size, void* d_ws, size_t ws_size,
                              hipStream_t stream) {
    const float* input    = (const float*)d_in[0];  // (16,2048,1024)
    const float* in_cache = (const float*)d_in[1];  // (16,512,19)
    const float* W_lin    = (const float*)d_in[2];  // (1024,512)
    const float* conv_w   = (const float*)d_in[3];  // (512,20)
    const float* W_aff    = (const float*)d_in[4];  // (512,1024)
    const float* b_aff    = (const float*)d_in[5];  // (1024,)
    float* out = (float*)d_out;                     // 33554432 + 155648 f32

    // workspace layout (bytes):
    //   [0, 32MB)       x bf16 (32768x512)
    //   [32MB, 64MB)    m bf16 (32768x512)
    //   [64MB, +1MB)    W_lin^T bf16 (512x1024)
    //   [65MB, +0.5MB)  W_aff^T bf16 (1024x512)
    char* ws = (char*)d_ws;
    bf16_t* x_buf = (bf16_t*)(ws);
    bf16_t* m_buf = (bf16_t*)(ws + 33554432);
    bf16_t* WlinT = (bf16_t*)(ws + 67108864);
    bf16_t* WaffT = (bf16_t*)(ws + 67108864 + 1048576);

    // 1. weight prep (both transposes, one launch)
    prep_weights<<<(DIN * DPJ + DPJ * DOUT + 255) / 256, 256, 0, stream>>>(
        W_lin, W_aff, WlinT, WaffT);

    // 2. x = bf16(input) @ W_lin   (M=32768, N=512, K=1024), fused async cast
    gemm1_fused<<<dim3(DPJ / 128, M_ROWS / 128), 256, 0, stream>>>(
        input, WlinT, x_buf, M_ROWS, DPJ, DIN);

    // 3. depthwise conv + residual -> m ; out_cache fused into last-t blocks
    dwconv_tiled<<<dim3(T_ / TT, B_, DPJ / PPT), 256, 0, stream>>>(
        x_buf, in_cache, conv_w, m_buf, out + OUT0_ELEMS);

    // 4. out = relu(m @ W_aff + b)  (M=32768, N=1024, K=512), f32 out
    gemm_bt_relu<<<dim3(DOUT / 128, M_ROWS / 128), 256, 0, stream>>>(
        m_buf, WaffT, out, b_aff, M_ROWS, DOUT, DPJ);
}